// Round 3
// baseline (871.275 us; speedup 1.0000x reference)
//
#include <hip/hip_runtime.h>

// GRU (reset_after) fused persistent kernel, MI355X gfx950.
// B=8192, T=256, F=64, H=50. One block = 16 batch rows, 4 waves.
// Per step: G[16,160] = [x_t | h] @ [W;U] via mfma_f32_16x16x32_bf16 with
// K split at 64 into two accumulators (lo = x@W, hi = h@U) so the
// reset_after h-gate gets xh and rh separately. Gates on VALU, h in regs,
// h re-written as bf16 directly in A-fragment layout in LDS.

typedef __attribute__((ext_vector_type(8))) short s16x8;
typedef __attribute__((ext_vector_type(4))) float f32x4;

#define T_STEPS 256
#define F_IN    64
#define GW      212   // LDS G row stride (floats): cols 0-159 gemm, 160-209 rh

__device__ __forceinline__ unsigned short f2bf(float f) {
  unsigned int u = __builtin_bit_cast(unsigned int, f);
  u += 0x7FFFu + ((u >> 16) & 1u);          // round-to-nearest-even
  return (unsigned short)(u >> 16);
}

__global__ __launch_bounds__(256, 2) void gru_fused(
    const float* __restrict__ x,  const float* __restrict__ W,
    const float* __restrict__ U,  const float* __restrict__ b,
    const float* __restrict__ Wd, const float* __restrict__ bdp,
    float* __restrict__ out)
{
  __shared__ __align__(16) unsigned short Abuf[2048]; // 4 K-chunk frags x 1KB
  __shared__ float G[16 * GW];
  __shared__ float bzs[64], brs[64], bh0[64], bh1[64];

  const int tid  = threadIdx.x;
  const int l    = tid & 63;
  const int w    = tid >> 6;          // wave id 0..3
  const int lhi  = l >> 4, llo = l & 15;
  const int row0 = blockIdx.x << 4;   // 16 rows per block

  // ---- stage combined biases (z,r use b0+b1; h keeps them separate) ----
  if (tid < 50) {
    bzs[tid] = b[tid]        + b[150 + tid];
    brs[tid] = b[50 + tid]   + b[200 + tid];
    bh0[tid] = b[100 + tid];
    bh1[tid] = b[250 + tid];
  }
  // zero h-region of A (k=64..127 incl. pad) => h(t=0)=0, pad stays 0 forever
  ((unsigned long long*)Abuf)[256 + tid] = 0ULL;

  // ---- B fragments in registers, loaded once. B = [W;U] (K=114 pad 128, N=150 pad 160).
  // wave w owns n-tiles {3w, 3w+1, 3w+2}; nt>=10 are dummy zero tiles (uniform code).
  s16x8 breg[3][4];
  #pragma unroll
  for (int wi = 0; wi < 3; ++wi) {
    const int nt  = w * 3 + wi;
    const int col = nt * 16 + llo;
    #pragma unroll
    for (int kc = 0; kc < 4; ++kc) {
      s16x8 f;
      #pragma unroll
      for (int i = 0; i < 8; ++i) {
        const int k = kc * 32 + lhi * 8 + i;
        float v = 0.f;
        if (col < 150 && k < 114)
          v = (k < 64) ? W[k * 150 + col] : U[(k - 64) * 150 + col];
        f[i] = (short)f2bf(v);
      }
      breg[wi][kc] = f;
    }
  }

  // ---- x loader: waves 0,1 each own one K-chunk frag (kc = w). Lane l holds
  // row=llo, k = w*32 + lhi*8 .. +7 (8 consecutive floats = 2 float4). ----
  const float* xlane =
      x + ((long)(row0 + llo) * T_STEPS) * F_IN + (w & 1) * 32 + lhi * 8;
  f32x4 xa = {0.f,0.f,0.f,0.f}, xb = xa;
  if (w < 2) {            // preload t=0
    xa = *(const f32x4*)(xlane + 0);
    xb = *(const f32x4*)(xlane + 4);
  }
  if (w < 2) {            // write x(0) frag in exact A-frag layout (linear 16B/lane)
    s16x8 f;
    f[0]=(short)f2bf(xa[0]); f[1]=(short)f2bf(xa[1]);
    f[2]=(short)f2bf(xa[2]); f[3]=(short)f2bf(xa[3]);
    f[4]=(short)f2bf(xb[0]); f[5]=(short)f2bf(xb[1]);
    f[6]=(short)f2bf(xb[2]); f[7]=(short)f2bf(xb[3]);
    *(s16x8*)((char*)Abuf + w * 1024 + l * 16) = f;
  }
  __syncthreads();

  float h0 = 0.f, h1 = 0.f, h2 = 0.f, h3 = 0.f;  // this thread's h units
  const int rowg = tid >> 4;   // gate row 0..15
  const int jg   = tid & 15;   // gate j = jg + 16*i

  for (int t = 0; t < T_STEPS; ++t) {
    // prefetch x(t+1) into regs (consumed after next barrier)
    int t1 = t + 1; if (t1 >= T_STEPS) t1 = T_STEPS - 1;
    if (w < 2) {
      const float* p = xlane + (long)t1 * F_IN;
      xa = *(const f32x4*)p;
      xb = *(const f32x4*)(p + 4);
    }

    // A fragments for this step (same for all waves; mt = 0 only)
    const char* Ab = (const char*)Abuf;
    s16x8 a0 = *(const s16x8*)(Ab +    0 + l * 16);
    s16x8 a1 = *(const s16x8*)(Ab + 1024 + l * 16);
    s16x8 a2 = *(const s16x8*)(Ab + 2048 + l * 16);
    s16x8 a3 = *(const s16x8*)(Ab + 3072 + l * 16);

    f32x4 lo[3], hi[3];
    #pragma unroll
    for (int wi = 0; wi < 3; ++wi) {
      f32x4 zlo = {0.f,0.f,0.f,0.f};
      zlo    = __builtin_amdgcn_mfma_f32_16x16x32_bf16(a0, breg[wi][0], zlo, 0,0,0);
      lo[wi] = __builtin_amdgcn_mfma_f32_16x16x32_bf16(a1, breg[wi][1], zlo, 0,0,0);
      f32x4 zhi = {0.f,0.f,0.f,0.f};
      zhi    = __builtin_amdgcn_mfma_f32_16x16x32_bf16(a2, breg[wi][2], zhi, 0,0,0);
      hi[wi] = __builtin_amdgcn_mfma_f32_16x16x32_bf16(a3, breg[wi][3], zhi, 0,0,0);
    }

    // write accumulators to G. C/D layout: col=lane&15, row=(lane>>4)*4+reg.
    #pragma unroll
    for (int wi = 0; wi < 3; ++wi) {
      const int nt = w * 3 + wi;
      if (nt < 10) {
        const int col = nt * 16 + llo;
        #pragma unroll
        for (int r = 0; r < 4; ++r) {
          const int row = lhi * 4 + r;
          const float vlo = lo[wi][r], vhi = hi[wi][r];
          G[row * GW + col] = (col < 100) ? (vlo + vhi) : vlo;   // z/r sum | xh
          if (col >= 100 && col < 150) G[row * GW + col + 60] = vhi; // rh
        }
      }
    }
    __syncthreads();

    // land x(t+1) into A-frag LDS (waves 0,1)
    if (w < 2) {
      s16x8 f;
      f[0]=(short)f2bf(xa[0]); f[1]=(short)f2bf(xa[1]);
      f[2]=(short)f2bf(xa[2]); f[3]=(short)f2bf(xa[3]);
      f[4]=(short)f2bf(xb[0]); f[5]=(short)f2bf(xb[1]);
      f[6]=(short)f2bf(xb[2]); f[7]=(short)f2bf(xb[3]);
      *(s16x8*)((char*)Abuf + w * 1024 + l * 16) = f;
    }

    // gates: thread (rowg, jg) handles j = jg, jg+16, jg+32 (+ jg+48 if jg<2)
    #pragma unroll
    for (int i = 0; i < 4; ++i) {
      if (i < 3 || jg < 2) {
        const int j = jg + 16 * i;
        const float* Gr = &G[rowg * GW];
        const float zs = Gr[j], rs = Gr[j + 50], xh = Gr[j + 100], rh = Gr[j + 160];
        const float z = __builtin_amdgcn_rcpf(1.f + __expf(-(zs + bzs[j])));
        const float r = __builtin_amdgcn_rcpf(1.f + __expf(-(rs + brs[j])));
        const float e = __expf(2.f * (xh + bh0[j] + r * (rh + bh1[j])));
        const float hh = 1.f - 2.f * __builtin_amdgcn_rcpf(1.f + e); // tanh
        const float hp = (i == 0) ? h0 : (i == 1) ? h1 : (i == 2) ? h2 : h3;
        const float hn = z * hp + (1.f - z) * hh;
        if (i == 0) h0 = hn; else if (i == 1) h1 = hn;
        else if (i == 2) h2 = hn; else h3 = hn;
        // store h as bf16 into A-frag layout at k = 64+j
        const int k = 64 + j, kc = k >> 5, kk = k & 31;
        Abuf[kc * 512 + ((kk >> 3) * 16 + rowg) * 8 + (kk & 7)] = f2bf(hn);
      }
    }
    __syncthreads();
  }

  // epilogue: out[row] = sum_j h[row][j] * Wd[j] + bd  (reduce 16 lanes/row)
  float p = h0 * Wd[jg] + h1 * Wd[jg + 16] + h2 * Wd[jg + 32];
  if (jg < 2) p += h3 * Wd[jg + 48];
  p += __shfl_xor(p, 1);
  p += __shfl_xor(p, 2);
  p += __shfl_xor(p, 4);
  p += __shfl_xor(p, 8);
  if (jg == 0) out[row0 + rowg] = p + bdp[0];
}

extern "C" void kernel_launch(void* const* d_in, const int* in_sizes, int n_in,
                              void* d_out, int out_size, void* d_ws, size_t ws_size,
                              hipStream_t stream) {
  const float* x   = (const float*)d_in[0];
  const float* W   = (const float*)d_in[1];
  const float* U   = (const float*)d_in[2];
  const float* b   = (const float*)d_in[3];
  const float* Wd  = (const float*)d_in[4];
  const float* bdp = (const float*)d_in[5];
  float* out = (float*)d_out;
  gru_fused<<<dim3(512), dim3(256), 0, stream>>>(x, W, U, b, Wd, bdp, out);
}

// Round 5
// 827.534 us; speedup vs baseline: 1.0529x; 1.0529x over previous
//
#include <hip/hip_runtime.h>
#include <hip/hip_bf16.h>

// GRU (reset_after) fused, MI355X gfx950. B=8192, T=256, F=64, H=50.
// Block = 16 batch rows, 4 waves. Gate-blocked B layout: wave w owns n-tiles
// {w (z), 4+w (r), 8+w (h)} so each lane's accumulators hold the full gate
// inputs for unit u=16w+(l&15), rows (l>>4)*4+r. No G roundtrip, 1 barrier
// per step, h/x double-buffered in LDS in exact MFMA A-fragment layout.

typedef __attribute__((ext_vector_type(8))) short s16x8;
typedef __attribute__((ext_vector_type(4))) short s16x4;
typedef __attribute__((ext_vector_type(4))) float f32x4;

#define TS 256

__device__ __forceinline__ unsigned short f2bf(float f) {
  return __builtin_bit_cast(unsigned short, __float2bfloat16(f));
}

__global__ __launch_bounds__(256, 2) void gru_fused(
    const float* __restrict__ x,  const float* __restrict__ W,
    const float* __restrict__ U,  const float* __restrict__ b,
    const float* __restrict__ Wd, const float* __restrict__ bdp,
    float* __restrict__ out)
{
  __shared__ __align__(16) unsigned short xbuf[2][2][512]; // [par][chunk k0/k1]
  __shared__ __align__(16) unsigned short hbuf[2][2][512]; // [par][chunk k2/k3]
  __shared__ float red[4][16];

  const int tid = threadIdx.x;
  const int l   = tid & 63;
  const int w   = tid >> 6;          // wave 0..3
  const int lhi = l >> 4, llo = l & 15;
  const int row0 = blockIdx.x << 4;
  const int u = (w << 4) + llo;      // this thread's hidden unit (pad >= 50)

  // zero hbuf[0] => h(t=0)=0; pad k=114..127 stays harmless (B rows zero)
  ((unsigned long long*)hbuf)[tid]       = 0ULL;
  ((unsigned long long*)hbuf)[tid + 256] = 0ULL;

  // per-thread biases in registers (z/r combine input+recurrent bias)
  float bz = 0.f, br = 0.f, bh0 = 0.f, bh1 = 0.f;
  if (u < 50) {
    bz  = b[u]       + b[150 + u];
    br  = b[50 + u]  + b[200 + u];
    bh0 = b[100 + u];
    bh1 = b[250 + u];
  }

  // B fragments, gate-blocked columns: g in {z,r,h} -> source col g*50+u.
  // kc 0,1 = W rows (k<64), kc 2,3 = U rows (k-64<50), else zero pad.
  s16x8 breg[3][4];
  #pragma unroll
  for (int g = 0; g < 3; ++g) {
    #pragma unroll
    for (int kc = 0; kc < 4; ++kc) {
      s16x8 f;
      #pragma unroll
      for (int i = 0; i < 8; ++i) {
        const int k = kc * 32 + lhi * 8 + i;
        float v = 0.f;
        if (u < 50 && k < 114)
          v = (k < 64) ? W[k * 150 + g * 50 + u]
                       : U[(k - 64) * 150 + g * 50 + u];
        f[i] = (short)f2bf(v);
      }
      breg[g][kc] = f;
    }
  }

  // balanced x staging: thread covers 4 f32 -> 4 bf16 of the A-frag.
  // slot: chunk sc, frag-lane sla (row=sla&15, koct=sla>>4), half shalf.
  const int sc    = tid >> 7;
  const int sla   = (tid >> 1) & 63;
  const int shalf = tid & 1;
  const float* xp = x + (long)(row0 + (sla & 15)) * (TS * 64)
                      + sc * 32 + (sla >> 4) * 8 + shalf * 4;
  unsigned short* const xdst0 = &xbuf[0][sc][sla * 8 + shalf * 4];
  unsigned short* const xdst1 = &xbuf[1][sc][sla * 8 + shalf * 4];

  // prologue: stage x(0) into xbuf[0]; preload x(1) into regs
  f32x4 xc = *(const f32x4*)xp;
  {
    s16x4 pk;
    pk[0] = (short)f2bf(xc[0]); pk[1] = (short)f2bf(xc[1]);
    pk[2] = (short)f2bf(xc[2]); pk[3] = (short)f2bf(xc[3]);
    *(s16x4*)xdst0 = pk;
  }
  xc = *(const f32x4*)(xp + 64);
  __syncthreads();

  float h0 = 0.f, h1 = 0.f, h2 = 0.f, h3 = 0.f;
  f32x4 xn;

#define GRU_STEP(T, XC, XN, PR, PW, XDST)                                      \
  {                                                                            \
    int tpre = (T) + 2; if (tpre > TS - 1) tpre = TS - 1;                      \
    XN = *(const f32x4*)(xp + (long)tpre * 64);                                \
    const s16x8 a0 = *(const s16x8*)&xbuf[PR][0][l * 8];                       \
    const s16x8 a1 = *(const s16x8*)&xbuf[PR][1][l * 8];                       \
    const s16x8 a2 = *(const s16x8*)&hbuf[PR][0][l * 8];                       \
    const s16x8 a3 = *(const s16x8*)&hbuf[PR][1][l * 8];                       \
    f32x4 lo[3], hi[3];                                                        \
    _Pragma("unroll")                                                          \
    for (int g = 0; g < 3; ++g) {                                              \
      f32x4 zz = {0.f, 0.f, 0.f, 0.f};                                         \
      zz    = __builtin_amdgcn_mfma_f32_16x16x32_bf16(a2, breg[g][2], zz, 0,0,0);\
      hi[g] = __builtin_amdgcn_mfma_f32_16x16x32_bf16(a3, breg[g][3], zz, 0,0,0);\
      f32x4 yy = {0.f, 0.f, 0.f, 0.f};                                         \
      yy    = __builtin_amdgcn_mfma_f32_16x16x32_bf16(a0, breg[g][0], yy, 0,0,0);\
      lo[g] = __builtin_amdgcn_mfma_f32_16x16x32_bf16(a1, breg[g][1], yy, 0,0,0);\
    }                                                                          \
    {                                                                          \
      s16x4 pk;                                                                \
      pk[0] = (short)f2bf(XC[0]); pk[1] = (short)f2bf(XC[1]);                  \
      pk[2] = (short)f2bf(XC[2]); pk[3] = (short)f2bf(XC[3]);                  \
      *(s16x4*)(XDST) = pk;                                                    \
    }                                                                          \
    _Pragma("unroll")                                                          \
    for (int r = 0; r < 4; ++r) {                                              \
      float hv = (r == 0) ? h0 : (r == 1) ? h1 : (r == 2) ? h2 : h3;           \
      const float zs = lo[0][r] + hi[0][r] + bz;                               \
      const float rs = lo[1][r] + hi[1][r] + br;                               \
      const float z  = __builtin_amdgcn_rcpf(1.f + __expf(-zs));               \
      const float rr = __builtin_amdgcn_rcpf(1.f + __expf(-rs));               \
      const float ar = lo[2][r] + bh0 + rr * (hi[2][r] + bh1);                 \
      const float e  = __expf(2.f * ar);                                       \
      const float hh = 1.f - 2.f * __builtin_amdgcn_rcpf(1.f + e);             \
      hv = hh + z * (hv - hh);                                                 \
      if (r == 0) h0 = hv; else if (r == 1) h1 = hv;                           \
      else if (r == 2) h2 = hv; else h3 = hv;                                  \
      hbuf[PW][u >> 5][(((u & 31) >> 3) * 16 + lhi * 4 + r) * 8 + (u & 7)] =   \
          f2bf(hv);                                                            \
    }                                                                          \
    __syncthreads();                                                           \
  }

  for (int t = 0; t < TS; t += 2) {
    GRU_STEP(t,     xc, xn, 0, 1, xdst1)
    GRU_STEP(t + 1, xn, xc, 1, 0, xdst0)
  }
#undef GRU_STEP

  // epilogue: out[row] = sum_u h[row][u]*Wd[u] + bd
  const float Wdv = (u < 50) ? Wd[u] : 0.f;
  float p0 = h0 * Wdv, p1 = h1 * Wdv, p2 = h2 * Wdv, p3 = h3 * Wdv;
  #pragma unroll
  for (int m = 1; m < 16; m <<= 1) {
    p0 += __shfl_xor(p0, m);
    p1 += __shfl_xor(p1, m);
    p2 += __shfl_xor(p2, m);
    p3 += __shfl_xor(p3, m);
  }
  if (llo == 0) {
    red[w][lhi * 4 + 0] = p0;
    red[w][lhi * 4 + 1] = p1;
    red[w][lhi * 4 + 2] = p2;
    red[w][lhi * 4 + 3] = p3;
  }
  __syncthreads();
  if (tid < 16)
    out[row0 + tid] =
        red[0][tid] + red[1][tid] + red[2][tid] + red[3][tid] + bdp[0];
}

extern "C" void kernel_launch(void* const* d_in, const int* in_sizes, int n_in,
                              void* d_out, int out_size, void* d_ws, size_t ws_size,
                              hipStream_t stream) {
  const float* x   = (const float*)d_in[0];
  const float* W   = (const float*)d_in[1];
  const float* U   = (const float*)d_in[2];
  const float* b   = (const float*)d_in[3];
  const float* Wd  = (const float*)d_in[4];
  const float* bdp = (const float*)d_in[5];
  float* out = (float*)d_out;
  gru_fused<<<dim3(512), dim3(256), 0, stream>>>(x, W, U, b, Wd, bdp, out);
}

// Round 6
// 783.743 us; speedup vs baseline: 1.1117x; 1.0559x over previous
//
#include <hip/hip_runtime.h>
#include <hip/hip_bf16.h>

// GRU (reset_after) fused, MI355X gfx950. B=8192, T=256, F=64, H=50.
// Block = 16 batch rows, 4 waves. Gate-blocked B columns: wave w owns n-tiles
// {z,r,h} for units u=16w+(l&15), so each lane's accumulators hold all gate
// inputs locally (no G roundtrip). 1 raw barrier/step (lgkmcnt-only: global
// x-prefetch loads stay in flight across barriers — no vmcnt(0) drain).
// x prefetched 4 steps deep in registers, h/x double-buffered in LDS in
// exact MFMA A-fragment layout.

typedef __attribute__((ext_vector_type(8))) short s16x8;
typedef __attribute__((ext_vector_type(4))) short s16x4;
typedef __attribute__((ext_vector_type(4))) float f32x4;

#define TS 256

__device__ __forceinline__ unsigned short f2bf(float f) {
  return __builtin_bit_cast(unsigned short, __float2bfloat16(f));
}

// LDS-visibility barrier WITHOUT vmcnt drain (T4 pattern, m201-verified).
#define RAWBAR()                                                \
  do {                                                          \
    asm volatile("s_waitcnt lgkmcnt(0)" ::: "memory");          \
    __builtin_amdgcn_sched_barrier(0);                          \
    __builtin_amdgcn_s_barrier();                               \
  } while (0)

__global__ __launch_bounds__(256, 2) void gru_fused(
    const float* __restrict__ x,  const float* __restrict__ W,
    const float* __restrict__ U,  const float* __restrict__ b,
    const float* __restrict__ Wd, const float* __restrict__ bdp,
    float* __restrict__ out)
{
  __shared__ __align__(16) unsigned short xbuf[2][2][512]; // [par][chunk k0/k1]
  __shared__ __align__(16) unsigned short hbuf[2][2][512]; // [par][chunk k2/k3]
  __shared__ float red[4][16];

  const int tid = threadIdx.x;
  const int l   = tid & 63;
  const int w   = tid >> 6;          // wave 0..3
  const int lhi = l >> 4, llo = l & 15;
  const int row0 = blockIdx.x << 4;
  const int u = (w << 4) + llo;      // this thread's hidden unit (pad >= 50)

  // zero hbuf[0] => h(t=0)=0; pad k=114..127 harmless (B rows zero)
  ((unsigned long long*)hbuf)[tid]       = 0ULL;
  ((unsigned long long*)hbuf)[tid + 256] = 0ULL;

  // per-thread biases (z/r combine input+recurrent bias)
  float bz = 0.f, br = 0.f, bh0 = 0.f, bh1 = 0.f;
  if (u < 50) {
    bz  = b[u]       + b[150 + u];
    br  = b[50 + u]  + b[200 + u];
    bh0 = b[100 + u];
    bh1 = b[250 + u];
  }

  // B fragments, gate-blocked columns: g in {z,r,h} -> source col g*50+u.
  s16x8 breg[3][4];
  #pragma unroll
  for (int g = 0; g < 3; ++g) {
    #pragma unroll
    for (int kc = 0; kc < 4; ++kc) {
      s16x8 f;
      #pragma unroll
      for (int i = 0; i < 8; ++i) {
        const int k = kc * 32 + lhi * 8 + i;
        float v = 0.f;
        if (u < 50 && k < 114)
          v = (k < 64) ? W[k * 150 + g * 50 + u]
                       : U[(k - 64) * 150 + g * 50 + u];
        f[i] = (short)f2bf(v);
      }
      breg[g][kc] = f;
    }
  }

  // balanced x staging: thread covers 4 f32 -> 4 bf16 of the A-frag.
  const int sc    = tid >> 7;
  const int sla   = (tid >> 1) & 63;
  const int shalf = tid & 1;
  const float* xp = x + (long)(row0 + (sla & 15)) * (TS * 64)
                      + sc * 32 + (sla >> 4) * 8 + shalf * 4;
  unsigned short* const xdst0 = &xbuf[0][sc][sla * 8 + shalf * 4];
  unsigned short* const xdst1 = &xbuf[1][sc][sla * 8 + shalf * 4];

  // prologue: stage x(0); preload x(1..4) into reg set A
  {
    const f32x4 x0 = *(const f32x4*)xp;
    s16x4 pk;
    pk[0] = (short)f2bf(x0[0]); pk[1] = (short)f2bf(x0[1]);
    pk[2] = (short)f2bf(x0[2]); pk[3] = (short)f2bf(x0[3]);
    *(s16x4*)xdst0 = pk;
  }
  f32x4 xA0 = *(const f32x4*)(xp + 1 * 64);
  f32x4 xA1 = *(const f32x4*)(xp + 2 * 64);
  f32x4 xA2 = *(const f32x4*)(xp + 3 * 64);
  f32x4 xA3 = *(const f32x4*)(xp + 4 * 64);
  f32x4 xB0, xB1, xB2, xB3;
  RAWBAR();

  float h0 = 0.f, h1 = 0.f, h2 = 0.f, h3 = 0.f;

// step T: issue load x(T+5) into NXT; compute from parity PR; convert CUR
// (= x(T+1)) into XDST (parity PR^1); h(T+1) -> hbuf[PR^1].
#define GRU_STEP(T, CUR, NXT, PR, XDST)                                        \
  {                                                                            \
    const int tl = ((T) + 5 > TS - 1) ? (TS - 1) : ((T) + 5);                  \
    NXT = *(const f32x4*)(xp + (long)tl * 64);                                 \
    const s16x8 a0 = *(const s16x8*)&xbuf[PR][0][l * 8];                       \
    const s16x8 a1 = *(const s16x8*)&xbuf[PR][1][l * 8];                       \
    const s16x8 a2 = *(const s16x8*)&hbuf[PR][0][l * 8];                       \
    const s16x8 a3 = *(const s16x8*)&hbuf[PR][1][l * 8];                       \
    f32x4 lo[3], hi[3];                                                        \
    _Pragma("unroll")                                                          \
    for (int g = 0; g < 3; ++g) {                                              \
      f32x4 zz = {0.f, 0.f, 0.f, 0.f};                                         \
      zz    = __builtin_amdgcn_mfma_f32_16x16x32_bf16(a2, breg[g][2], zz, 0,0,0);\
      hi[g] = __builtin_amdgcn_mfma_f32_16x16x32_bf16(a3, breg[g][3], zz, 0,0,0);\
      f32x4 yy = {0.f, 0.f, 0.f, 0.f};                                         \
      yy    = __builtin_amdgcn_mfma_f32_16x16x32_bf16(a0, breg[g][0], yy, 0,0,0);\
      lo[g] = __builtin_amdgcn_mfma_f32_16x16x32_bf16(a1, breg[g][1], yy, 0,0,0);\
    }                                                                          \
    {                                                                          \
      s16x4 pk;                                                                \
      pk[0] = (short)f2bf(CUR[0]); pk[1] = (short)f2bf(CUR[1]);                \
      pk[2] = (short)f2bf(CUR[2]); pk[3] = (short)f2bf(CUR[3]);                \
      *(s16x4*)(XDST) = pk;                                                    \
    }                                                                          \
    _Pragma("unroll")                                                          \
    for (int r = 0; r < 4; ++r) {                                              \
      float hv = (r == 0) ? h0 : (r == 1) ? h1 : (r == 2) ? h2 : h3;           \
      const float zs = lo[0][r] + hi[0][r] + bz;                               \
      const float rs = lo[1][r] + hi[1][r] + br;                               \
      const float z  = __builtin_amdgcn_rcpf(1.f + __expf(-zs));               \
      const float rr = __builtin_amdgcn_rcpf(1.f + __expf(-rs));               \
      const float ar = lo[2][r] + bh0 + rr * (hi[2][r] + bh1);                 \
      const float e  = __expf(2.f * ar);                                       \
      const float hh = 1.f - 2.f * __builtin_amdgcn_rcpf(1.f + e);             \
      hv = hh + z * (hv - hh);                                                 \
      if (r == 0) h0 = hv; else if (r == 1) h1 = hv;                           \
      else if (r == 2) h2 = hv; else h3 = hv;                                  \
      hbuf[(PR) ^ 1][u >> 5]                                                   \
          [(((u & 31) >> 3) * 16 + lhi * 4 + r) * 8 + (u & 7)] = f2bf(hv);     \
    }                                                                          \
    RAWBAR();                                                                  \
  }

  for (int t = 0; t < TS; t += 8) {
    GRU_STEP(t + 0, xA0, xB0, 0, xdst1)
    GRU_STEP(t + 1, xA1, xB1, 1, xdst0)
    GRU_STEP(t + 2, xA2, xB2, 0, xdst1)
    GRU_STEP(t + 3, xA3, xB3, 1, xdst0)
    GRU_STEP(t + 4, xB0, xA0, 0, xdst1)
    GRU_STEP(t + 5, xB1, xA1, 1, xdst0)
    GRU_STEP(t + 6, xB2, xA2, 0, xdst1)
    GRU_STEP(t + 7, xB3, xA3, 1, xdst0)
  }
#undef GRU_STEP

  // epilogue: out[row] = sum_u h[row][u]*Wd[u] + bd
  const float Wdv = (u < 50) ? Wd[u] : 0.f;
  float p0 = h0 * Wdv, p1 = h1 * Wdv, p2 = h2 * Wdv, p3 = h3 * Wdv;
  #pragma unroll
  for (int m = 1; m < 16; m <<= 1) {
    p0 += __shfl_xor(p0, m);
    p1 += __shfl_xor(p1, m);
    p2 += __shfl_xor(p2, m);
    p3 += __shfl_xor(p3, m);
  }
  if (llo == 0) {
    red[w][lhi * 4 + 0] = p0;
    red[w][lhi * 4 + 1] = p1;
    red[w][lhi * 4 + 2] = p2;
    red[w][lhi * 4 + 3] = p3;
  }
  __syncthreads();
  if (tid < 16)
    out[row0 + tid] =
        red[0][tid] + red[1][tid] + red[2][tid] + red[3][tid] + bdp[0];
}

extern "C" void kernel_launch(void* const* d_in, const int* in_sizes, int n_in,
                              void* d_out, int out_size, void* d_ws, size_t ws_size,
                              hipStream_t stream) {
  const float* x   = (const float*)d_in[0];
  const float* W   = (const float*)d_in[1];
  const float* U   = (const float*)d_in[2];
  const float* b   = (const float*)d_in[3];
  const float* Wd  = (const float*)d_in[4];
  const float* bdp = (const float*)d_in[5];
  float* out = (float*)d_out;
  gru_fused<<<dim3(512), dim3(256), 0, stream>>>(x, W, U, b, Wd, bdp, out);
}